// Round 6
// baseline (31.656 us; speedup 1.0000x reference)
//
#include <hip/hip_runtime.h>

#define NN 8192
#define BB 1024
#define KK 8
#define CC 10
#define NT 512
#define ROWS 2
#define GRID (BB/ROWS)   // 512
#define CHUNK (NN/NT)    // 16
#define NW (NT/64)       // 8 waves
#define T3SZ 2100        // [0,1000): concepts 0-2 | [1000,2000): 3-5 | [2000,2100): 6-7 (+A)

// LDS row-buffer swizzle: rotate column by row index -> both chunked and
// strided access patterns stay <=2-way per bank (free, per m136).
__device__ __forceinline__ int swz(int n) {
    return (n & ~31) | ((n + (n >> 5)) & 31);
}

__global__ void pack_kernel(const int* __restrict__ c_in, const int* __restrict__ delta_in,
                            unsigned* __restrict__ pairs, unsigned* __restrict__ dmask_g) {
    int n = blockIdx.x * blockDim.x + threadIdx.x;
    if (n >= NN) return;
    const int4* p = reinterpret_cast<const int4*>(c_in + (size_t)n * KK);
    int4 lo = p[0], hi = p[1];
    unsigned g0 = (unsigned)((lo.x * 10 + lo.y) * 10 + lo.z);   // 0..999
    unsigned g1 = (unsigned)((lo.w * 10 + hi.x) * 10 + hi.y);   // 0..999
    unsigned g2 = (unsigned)(hi.z * 10 + hi.w);                 // 0..99
    pairs[n] = g0 | (g1 << 10) | (g2 << 20);
    // delta bitmask: word w covers n in [32w, 32w+32)
    unsigned long long bal = __ballot(delta_in[n] & 1);
    if ((threadIdx.x & 63) == 0) {
        dmask_g[n >> 5]       = (unsigned)(bal & 0xffffffffull);
        dmask_g[(n >> 5) + 1] = (unsigned)(bal >> 32);
    }
}

// exclusive block scan of v over NT threads; also returns the block total.
// ws must be a fresh float[NW] slot per call.
__device__ __forceinline__ float block_excl_scan(float v, int lane, int wv, float* ws,
                                                 float* total) {
    float x = v;
    #pragma unroll
    for (int d = 1; d < 64; d <<= 1) {
        float y = __shfl_up(x, d);
        if (lane >= d) x += y;
    }
    if (lane == 63) ws[wv] = x;
    __syncthreads();
    float off = x - v, tot = 0.0f;
    #pragma unroll
    for (int w = 0; w < NW; w++) {
        float y = ws[w];              // broadcast reads, conflict-free
        tot += y;
        if (w < wv) off += y;
    }
    *total = tot;
    return off;
}

__global__ __launch_bounds__(NT, 4) void beran_kernel(
    const float* __restrict__ c_p, const float* __restrict__ bandwidth,
    const int* __restrict__ c_in, const int* __restrict__ delta_in,
    const unsigned* __restrict__ pairs, const unsigned* __restrict__ dmask_g,
    float* __restrict__ out)
{
    __shared__ float a[NN];             // 32 KB swizzled surv buffer (epilogue transpose)
    __shared__ float tb[ROWS][KK * CC]; // per-row single-concept tables
    __shared__ float Apart[ROWS][KK];
    __shared__ float t3[ROWS][T3SZ];    // negated triple/pair tables, A folded in
    __shared__ float wss[ROWS][2][NW];  // distinct scan slots per (row, scan)

    const int t    = threadIdx.x;
    const int lane = t & 63;
    const int wv   = t >> 6;
    const int base = t * CHUNK;
    const int b0   = blockIdx.x * ROWS;

    // ---- softmax + per-concept metric rows for BOTH b-rows ----
    if (t < ROWS * KK) {
        const int r = t >> 3, k = t & 7;
        const int b = b0 + r;
        float v[CC];
        float mx = -1e30f;
        #pragma unroll
        for (int c = 0; c < CC; c++) { v[c] = c_p[((size_t)b*KK + k)*CC + c]; mx = fmaxf(mx, v[c]); }
        float se = 0.0f;
        #pragma unroll
        for (int c = 0; c < CC; c++) { v[c] = __expf(v[c] - mx); se += v[c]; }
        float inv = 1.0f / se;
        float Ak = 0.0f;
        #pragma unroll
        for (int c = 0; c < CC; c++) {
            float p  = v[c] * inv;
            float bw = bandwidth[k*CC + c];
            bw = fminf(fmaxf(bw, 0.001f), 10.0f);
            float ib = 1.0f / bw;
            tb[r][k*CC + c] = ib - 2.0f * p * ib;
            Ak += p * p * ib;
        }
        Apart[r][k] = Ak;
    }
    __syncthreads();

    // ---- build negated 3-gather tables (both rows): 4200 entries / 512 thr ----
    for (int e = t; e < ROWS * T3SZ; e += NT) {
        const int r = e / T3SZ;
        const int i = e - r * T3SZ;
        float v;
        if (i < 1000) {
            v = tb[r][0*CC + i/100] + tb[r][1*CC + (i/10)%10] + tb[r][2*CC + i%10];
        } else if (i < 2000) {
            int j = i - 1000;
            v = tb[r][3*CC + j/100] + tb[r][4*CC + (j/10)%10] + tb[r][5*CC + j%10];
        } else {
            int q = i - 2000;
            float Ar = 0.0f;
            #pragma unroll
            for (int k = 0; k < KK; k++) Ar += Apart[r][k];
            v = tb[r][6*CC + q/10] + tb[r][7*CC + q%10] + Ar;
        }
        t3[r][i] = -v;
    }
    __syncthreads();

    // ---- load packed gather indices + delta mask ONCE (reused for both rows) ----
    unsigned pk[CHUNK];
    unsigned dm = 0;
    if (pairs) {
        #pragma unroll
        for (int g = 0; g < CHUNK / 4; g++) {
            uint4 v = *reinterpret_cast<const uint4*>(pairs + base + g * 4);
            pk[g*4+0] = v.x; pk[g*4+1] = v.y; pk[g*4+2] = v.z; pk[g*4+3] = v.w;
        }
        unsigned dm32 = dmask_g[t >> 1];
        dm = (dm32 >> ((t & 1) * 16)) & 0xffffu;
    } else {
        #pragma unroll
        for (int i = 0; i < CHUNK; i++) {
            const int4* p4 = reinterpret_cast<const int4*>(c_in + (size_t)(base + i) * KK);
            int4 lo = p4[0], hi = p4[1];
            unsigned g0 = (unsigned)((lo.x * 10 + lo.y) * 10 + lo.z);
            unsigned g1 = (unsigned)((lo.w * 10 + hi.x) * 10 + hi.y);
            unsigned g2 = (unsigned)(hi.z * 10 + hi.w);
            pk[i] = g0 | (g1 << 10) | (g2 << 20);
            dm |= (unsigned)(delta_in[base + i] & 1) << i;
        }
    }

    // ---- per-row pipeline; row r+1's compute overlaps row r's store drain ----
    #pragma unroll
    for (int r = 0; r < ROWS; r++) {
        const float* t3r = t3[r];

        // pass A (registers): raw weight cumsum via 3 LDS gathers/element
        float creg[CHUNK];
        float run = 0.0f;
        #pragma unroll
        for (int i = 0; i < CHUNK; i++) {
            unsigned w0 = pk[i];
            float m = t3r[w0 & 1023] + t3r[1000 + ((w0 >> 10) & 1023)]
                    + t3r[2000 + (w0 >> 20)];
            run += __expf(m);          // tables hold -(A + sum t)
            creg[i] = run;
        }

        // scan 1: block-exclusive offset + total weight sum
        // (this barrier also fences row r-1's pass-E reads of a[])
        float s;
        const float off_raw = block_excl_scan(run, lane, wv, wss[r][0], &s);
        const float invs = (s < 1e-13f) ? 0.0f : 1.0f / s;

        // pass C (registers): xi + hazard cumsum, one log per element
        const float ISO = 1.00001e-5f;   // atol + rtol*|1|
        float csprev = off_raw * invs;   // t==0 -> 0
        float Lprev  = __logf(1.0f - csprev);
        float run2 = 0.0f;
        #pragma unroll
        for (int i = 0; i < CHUNK; i++) {
            float cs = (creg[i] + off_raw) * invs;
            float L  = __logf(1.0f - cs);
            bool bad = (fabsf(csprev - 1.0f) <= ISO) || (fabsf(cs - 1.0f) <= ISO);
            float xi = bad ? 0.0f : (Lprev - L);
            float f  = ((dm >> i) & 1u) ? xi : 0.0f;
            run2 += f;
            creg[i] = run2;
            csprev = cs;
            Lprev  = L;
        }

        // scan 2: hazard offsets
        float H;
        const float off2 = block_excl_scan(run2, lane, wv, wss[r][1], &H);

        // pass D (chunked write): surv_func into swizzled LDS
        #pragma unroll
        for (int i = 0; i < CHUNK; i++) a[swz(base + i)] = __expf(-(creg[i] + off2));
        __syncthreads();

        // pass E (strided float4): coalesced global writes of surv + steps
        const float surv_last = a[swz(NN - 1)];          // broadcast
        const float ss = 1.0f - surv_last;               // telescoped step sum
        const float invss = (ss < 1e-13f) ? 0.0f : 1.0f / ss;
        const int b = b0 + r;
        float* outS = out + (size_t)b * NN;
        float* outT = out + (size_t)BB * NN + (size_t)b * NN;
        #pragma unroll
        for (int j = 0; j < NN / (NT * 4); j++) {        // 4 iterations
            int n0 = j * NT * 4 + t * 4;
            float s0 = a[swz(n0)];
            float s1 = a[swz(n0 + 1)];
            float s2 = a[swz(n0 + 2)];
            float s3 = a[swz(n0 + 3)];
            float sp = (n0 == 0) ? 1.0f : a[swz(n0 - 1)];
            *reinterpret_cast<float4*>(outS + n0) = make_float4(s0, s1, s2, s3);
            *reinterpret_cast<float4*>(outT + n0) =
                make_float4((sp - s0) * invss, (s0 - s1) * invss,
                            (s1 - s2) * invss, (s2 - s3) * invss);
        }
        // no trailing barrier: next row's scan-1 barrier fences a[] reuse
    }
}

extern "C" void kernel_launch(void* const* d_in, const int* in_sizes, int n_in,
                              void* d_out, int out_size, void* d_ws, size_t ws_size,
                              hipStream_t stream) {
    const float* c_p       = (const float*)d_in[0];
    const float* bandwidth = (const float*)d_in[1];
    const int*   c_in      = (const int*)d_in[2];
    const int*   delta_in  = (const int*)d_in[3];
    float* out = (float*)d_out;

    unsigned* pairs   = nullptr;
    unsigned* dmask_g = nullptr;
    const size_t need = (size_t)NN * sizeof(unsigned) + (size_t)(NN / 32) * sizeof(unsigned);
    if (ws_size >= need) {
        pairs   = (unsigned*)d_ws;
        dmask_g = (unsigned*)((char*)d_ws + (size_t)NN * sizeof(unsigned));
        pack_kernel<<<NN / 256, 256, 0, stream>>>(c_in, delta_in, pairs, dmask_g);
    }
    beran_kernel<<<GRID, NT, 0, stream>>>(c_p, bandwidth, c_in, delta_in, pairs, dmask_g, out);
}